// Round 1
// baseline (248.229 us; speedup 1.0000x reference)
//
#include <hip/hip_runtime.h>
#include <math.h>

#define KS    31
#define PADV  15
#define IMG   320
#define NOUT  289          // 320 - 31 = 289 valid centered outputs (i in [15, 304))
#define TILE  16
#define LT    (TILE + KS - 1)   // 46

__device__ __forceinline__ unsigned int ordkey(float f) {
    unsigned int b = __float_as_uint(f);
    return (b & 0x80000000u) ? ~b : (b | 0x80000000u);
}
__device__ __forceinline__ float ordval(unsigned int k) {
    unsigned int b = (k & 0x80000000u) ? (k & 0x7FFFFFFFu) : ~k;
    return __uint_as_float(b);
}

__global__ void init_mm(unsigned int* mm) {
    mm[0] = 0xFFFFFFFFu;   // running-min key
    mm[1] = 0u;            // running-max key
}

__global__ __launch_bounds__(256) void gabor_main(
    const float* __restrict__ fp, const int* __restrict__ fmap,
    const int* __restrict__ tmap, float* __restrict__ out,
    unsigned int* __restrict__ mm)
{
    __shared__ float tile[LT * LT];
    const int bh = blockIdx.y * TILE;
    const int bw = blockIdx.x * TILE;
    const int tid = threadIdx.x;

    // stage fprint window tile (46x46) into LDS
    for (int i = tid; i < LT * LT; i += 256) {
        int r = i / LT, c = i - r * LT;
        int gr = bh + r, gc = bw + c;
        tile[i] = (gr < IMG && gc < IMG) ? fp[gr * IMG + gc] : 0.0f;
    }
    __syncthreads();

    const int tx = tid & (TILE - 1), ty = tid >> 4;
    const int oy = bh + ty, ox = bw + tx;      // inner-region coords [0,289)

    float vmin = INFINITY, vmax = -INFINITY;

    if (oy < NOUT && ox < NOUT) {
        const int iy = oy + PADV, ix = ox + PADV;
        // theta = theta_int / 180 * pi  (match reference op order)
        float th = ((float)tmap[iy * IMG + ix] / 180.0f) * 3.14159265358979323846f;
        float f0 = 0.025f + 0.0015f * (float)fmap[iy * IMG + ix];
        float st, ct;
        sincosf(th, &st, &ct);
        const float fch = f0 * (1.0f / 45.0f);          // f0/3 / half
        const float TWO_PI = 6.28318530717958647692f;

        float acc = 0.0f;
        for (int dy = 0; dy < KS; ++dy) {
            const float y   = (float)(dy - PADV);
            const float yct = y * ct, yst = y * st;
            const float* trow = &tile[(ty + dy) * LT + tx];
            for (int dx = 0; dx < KS; ++dx) {
                float x   = (float)(dx - PADV);
                float x_t = fmaf(x,  ct, yst);           //  x*ct + y*st
                float y_t = fmaf(-x, st, yct);           // -x*st + y*ct
                float f_local = fmaf(fch, y_t, f0);
                float gamma   = fmaf(0.04f, fabsf(y_t), 1.0f);   // 1 + 0.6*|y_t|/15
                float gyt = gamma * y_t;
                float e = expf(-(x_t * x_t + gyt * gyt) * (1.0f / 72.0f));
                float c = cosf(TWO_PI * f_local * x_t);
                acc = fmaf(trow[dx], e * c, acc);
            }
        }
        out[iy * IMG + ix] = acc;
        vmin = acc; vmax = acc;
    }

    // wave64 min/max reduce, then one atomic pair per wave
    for (int off = 32; off > 0; off >>= 1) {
        vmin = fminf(vmin, __shfl_down(vmin, off, 64));
        vmax = fmaxf(vmax, __shfl_down(vmax, off, 64));
    }
    if ((tid & 63) == 0) {
        atomicMin(&mm[0], ordkey(vmin));
        atomicMax(&mm[1], ordkey(vmax));
    }
}

__global__ __launch_bounds__(256) void border_copy(
    const float* __restrict__ fp, float* __restrict__ out,
    unsigned int* __restrict__ mm)
{
    int p = blockIdx.x * 256 + threadIdx.x;
    float vmin = INFINITY, vmax = -INFINITY;
    if (p < IMG * IMG) {
        int i = p / IMG, j = p - i * IMG;
        bool inner = (i >= PADV) && (i < PADV + NOUT) && (j >= PADV) && (j < PADV + NOUT);
        if (!inner) {
            float v = fp[p];
            out[p] = v;
            vmin = v; vmax = v;
        }
    }
    for (int off = 32; off > 0; off >>= 1) {
        vmin = fminf(vmin, __shfl_down(vmin, off, 64));
        vmax = fmaxf(vmax, __shfl_down(vmax, off, 64));
    }
    if ((threadIdx.x & 63) == 0) {
        atomicMin(&mm[0], ordkey(vmin));
        atomicMax(&mm[1], ordkey(vmax));
    }
}

__global__ __launch_bounds__(256) void finalize(
    float* __restrict__ out, const unsigned int* __restrict__ mm)
{
    int p = blockIdx.x * 256 + threadIdx.x;
    if (p >= IMG * IMG) return;
    float mn = ordval(mm[0]);
    float mx = ordval(mm[1]) - mn;       // max(out - min) == max0 - min0
    float v  = out[p] - mn;
    if (mx != 0.0f) v = v / mx * 100.0f;
    out[p] = (v > 55.0f) ? 100.0f : 0.0f;
}

extern "C" void kernel_launch(void* const* d_in, const int* in_sizes, int n_in,
                              void* d_out, int out_size, void* d_ws, size_t ws_size,
                              hipStream_t stream) {
    const float* fp   = (const float*)d_in[0];
    const int*   fmap = (const int*)d_in[1];
    const int*   tmap = (const int*)d_in[2];
    float* out = (float*)d_out;
    unsigned int* mm = (unsigned int*)d_ws;

    hipLaunchKernelGGL(init_mm, dim3(1), dim3(1), 0, stream, mm);

    dim3 g((NOUT + TILE - 1) / TILE, (NOUT + TILE - 1) / TILE);   // 19 x 19
    hipLaunchKernelGGL(gabor_main, g, dim3(256), 0, stream, fp, fmap, tmap, out, mm);

    int nblk = (IMG * IMG + 255) / 256;
    hipLaunchKernelGGL(border_copy, dim3(nblk), dim3(256), 0, stream, fp, out, mm);
    hipLaunchKernelGGL(finalize,    dim3(nblk), dim3(256), 0, stream, out, mm);
}

// Round 2
// 212.187 us; speedup vs baseline: 1.1699x; 1.1699x over previous
//
#include <hip/hip_runtime.h>
#include <math.h>

#define KS    31
#define PADV  15
#define IMG   320
#define NOUT  289          // valid centered outputs (i in [15, 304))
#define NTH   180
#define NFR   20
#define NKER  (NTH * NFR)          // 3600 distinct kernels
#define KPAD  1024                 // 32x32 padded kernel (row stride 32)
#define KT_BYTES ((size_t)NKER * KPAD * 4)

#define TB    8                    // conv output tile 8x8
#define LROWS 39
#define LCOLS 39

__device__ __forceinline__ unsigned int ordkey(float f) {
    unsigned int b = __float_as_uint(f);
    return (b & 0x80000000u) ? ~b : (b | 0x80000000u);
}
__device__ __forceinline__ float ordval(unsigned int k) {
    unsigned int b = (k & 0x80000000u) ? (k & 0x7FFFFFFFu) : ~k;
    return __uint_as_float(b);
}

__global__ void init_mm(unsigned int* mm) {
    mm[0] = 0xFFFFFFFFu;   // running-min key
    mm[1] = 0u;            // running-max key
}

// ---- Build the 3600-kernel table: one block per (theta,freq) pair ----
__global__ __launch_bounds__(256) void build_ktab(float* __restrict__ ktab) {
    const int kidx = blockIdx.x;           // t*20 + f
    const int t = kidx / NFR, f = kidx - t * NFR;
    const float th = ((float)t / 180.0f) * 3.14159265358979323846f;
    const float f0 = 0.025f + 0.0015f * (float)f;
    float st, ct;
    sincosf(th, &st, &ct);
    const float fch = f0 * (1.0f / 45.0f);           // (f0/3)/half
    const float TWO_PI = 6.28318530717958647692f;

    float* base = ktab + (size_t)kidx * KPAD;
    #pragma unroll
    for (int g = 0; g < 4; ++g) {
        int e = g * 256 + threadIdx.x;
        int dy = e >> 5, dx = e & 31;
        float val = 0.0f;
        if (dy < KS && dx < KS) {
            float y = (float)(dy - PADV);
            float x = (float)(dx - PADV);
            float x_t = fmaf(x,  ct, y * st);
            float y_t = fmaf(-x, st, y * ct);
            float f_local = fmaf(fch, y_t, f0);
            float gamma   = fmaf(0.04f, fabsf(y_t), 1.0f);
            float gyt = gamma * y_t;
            float env = expf(-(x_t * x_t + gyt * gyt) * (1.0f / 72.0f));
            val = env * cosf(TWO_PI * f_local * x_t);
        }
        base[e] = val;
    }
}

// ---- Conv: one wave per output pixel, 64 lanes split the 1024 taps ----
__global__ __launch_bounds__(256) void gabor_conv(
    const float* __restrict__ fp, const int* __restrict__ fmap,
    const int* __restrict__ tmap, const float* __restrict__ ktab,
    float* __restrict__ out, unsigned int* __restrict__ mm)
{
    __shared__ float tile[LROWS * LCOLS];
    __shared__ int kpix[TB * TB];
    const int bh = blockIdx.y * TB;
    const int bw = blockIdx.x * TB;
    const int tid = threadIdx.x;

    for (int i = tid; i < LROWS * LCOLS; i += 256) {
        int r = i / LCOLS, c = i - r * LCOLS;
        int gr = bh + r, gc = bw + c;
        tile[i] = (gr < IMG && gc < IMG) ? fp[gr * IMG + gc] : 0.0f;
    }
    if (tid < TB * TB) {
        int py = tid >> 3, px = tid & 7;
        int oy = bh + py, ox = bw + px;
        int kidx = 0;
        if (oy < NOUT && ox < NOUT) {
            int iy = oy + PADV, ix = ox + PADV;
            kidx = tmap[iy * IMG + ix] * NFR + fmap[iy * IMG + ix];
        }
        kpix[tid] = kidx;
    }
    __syncthreads();

    const int wave = tid >> 6, lane = tid & 63;
    const int l3 = lane >> 3, l7 = lane & 7;
    float vmin = INFINITY, vmax = -INFINITY;

    for (int p = wave * 16; p < wave * 16 + 16; ++p) {
        int py = p >> 3, px = p & 7;
        int oy = bh + py, ox = bw + px;
        if (oy >= NOUT || ox >= NOUT) continue;
        const float4* kb = (const float4*)(ktab + (size_t)kpix[p] * KPAD);
        float acc = 0.0f;
        #pragma unroll
        for (int g = 0; g < 4; ++g) {
            float4 kv = kb[g * 64 + lane];
            const float* tr = &tile[(py + 8 * g + l3) * LCOLS + (px + 4 * l7)];
            acc = fmaf(tr[0], kv.x, acc);
            acc = fmaf(tr[1], kv.y, acc);
            acc = fmaf(tr[2], kv.z, acc);
            acc = fmaf(tr[3], kv.w, acc);
        }
        for (int off = 32; off; off >>= 1) acc += __shfl_down(acc, off, 64);
        if (lane == 0) {
            out[(oy + PADV) * IMG + (ox + PADV)] = acc;
            vmin = fminf(vmin, acc);
            vmax = fmaxf(vmax, acc);
        }
    }
    if (lane == 0) {
        atomicMin(&mm[0], ordkey(vmin));
        atomicMax(&mm[1], ordkey(vmax));
    }
}

// ---- Fallback (round-1 kernel) if ws is too small for the table ----
#define FTILE 16
#define FLT   (FTILE + KS - 1)
__global__ __launch_bounds__(256) void gabor_main(
    const float* __restrict__ fp, const int* __restrict__ fmap,
    const int* __restrict__ tmap, float* __restrict__ out,
    unsigned int* __restrict__ mm)
{
    __shared__ float tile[FLT * FLT];
    const int bh = blockIdx.y * FTILE;
    const int bw = blockIdx.x * FTILE;
    const int tid = threadIdx.x;
    for (int i = tid; i < FLT * FLT; i += 256) {
        int r = i / FLT, c = i - r * FLT;
        int gr = bh + r, gc = bw + c;
        tile[i] = (gr < IMG && gc < IMG) ? fp[gr * IMG + gc] : 0.0f;
    }
    __syncthreads();
    const int tx = tid & (FTILE - 1), ty = tid >> 4;
    const int oy = bh + ty, ox = bw + tx;
    float vmin = INFINITY, vmax = -INFINITY;
    if (oy < NOUT && ox < NOUT) {
        const int iy = oy + PADV, ix = ox + PADV;
        float th = ((float)tmap[iy * IMG + ix] / 180.0f) * 3.14159265358979323846f;
        float f0 = 0.025f + 0.0015f * (float)fmap[iy * IMG + ix];
        float st, ct;
        sincosf(th, &st, &ct);
        const float fch = f0 * (1.0f / 45.0f);
        const float TWO_PI = 6.28318530717958647692f;
        float acc = 0.0f;
        for (int dy = 0; dy < KS; ++dy) {
            const float y = (float)(dy - PADV);
            const float yct = y * ct, yst = y * st;
            const float* trow = &tile[(ty + dy) * FLT + tx];
            for (int dx = 0; dx < KS; ++dx) {
                float x = (float)(dx - PADV);
                float x_t = fmaf(x,  ct, yst);
                float y_t = fmaf(-x, st, yct);
                float f_local = fmaf(fch, y_t, f0);
                float gamma   = fmaf(0.04f, fabsf(y_t), 1.0f);
                float gyt = gamma * y_t;
                float e = expf(-(x_t * x_t + gyt * gyt) * (1.0f / 72.0f));
                float c = cosf(TWO_PI * f_local * x_t);
                acc = fmaf(trow[dx], e * c, acc);
            }
        }
        out[iy * IMG + ix] = acc;
        vmin = acc; vmax = acc;
    }
    for (int off = 32; off; off >>= 1) {
        vmin = fminf(vmin, __shfl_down(vmin, off, 64));
        vmax = fmaxf(vmax, __shfl_down(vmax, off, 64));
    }
    if ((tid & 63) == 0) {
        atomicMin(&mm[0], ordkey(vmin));
        atomicMax(&mm[1], ordkey(vmax));
    }
}

__global__ __launch_bounds__(256) void border_copy(
    const float* __restrict__ fp, float* __restrict__ out,
    unsigned int* __restrict__ mm)
{
    int p = blockIdx.x * 256 + threadIdx.x;
    float vmin = INFINITY, vmax = -INFINITY;
    if (p < IMG * IMG) {
        int i = p / IMG, j = p - i * IMG;
        bool inner = (i >= PADV) && (i < PADV + NOUT) && (j >= PADV) && (j < PADV + NOUT);
        if (!inner) {
            float v = fp[p];
            out[p] = v;
            vmin = v; vmax = v;
        }
    }
    for (int off = 32; off; off >>= 1) {
        vmin = fminf(vmin, __shfl_down(vmin, off, 64));
        vmax = fmaxf(vmax, __shfl_down(vmax, off, 64));
    }
    if ((threadIdx.x & 63) == 0) {
        atomicMin(&mm[0], ordkey(vmin));
        atomicMax(&mm[1], ordkey(vmax));
    }
}

__global__ __launch_bounds__(256) void finalize(
    float* __restrict__ out, const unsigned int* __restrict__ mm)
{
    int p = blockIdx.x * 256 + threadIdx.x;
    if (p >= IMG * IMG) return;
    float mn = ordval(mm[0]);
    float mx = ordval(mm[1]) - mn;
    float v  = out[p] - mn;
    if (mx != 0.0f) v = v / mx * 100.0f;
    out[p] = (v > 55.0f) ? 100.0f : 0.0f;
}

extern "C" void kernel_launch(void* const* d_in, const int* in_sizes, int n_in,
                              void* d_out, int out_size, void* d_ws, size_t ws_size,
                              hipStream_t stream) {
    const float* fp   = (const float*)d_in[0];
    const int*   fmap = (const int*)d_in[1];
    const int*   tmap = (const int*)d_in[2];
    float* out = (float*)d_out;
    unsigned int* mm = (unsigned int*)d_ws;

    hipLaunchKernelGGL(init_mm, dim3(1), dim3(1), 0, stream, mm);

    const size_t need = 256 + KT_BYTES;
    if (ws_size >= need) {
        float* ktab = (float*)((char*)d_ws + 256);
        hipLaunchKernelGGL(build_ktab, dim3(NKER), dim3(256), 0, stream, ktab);
        dim3 g((NOUT + TB - 1) / TB, (NOUT + TB - 1) / TB);   // 37 x 37
        hipLaunchKernelGGL(gabor_conv, g, dim3(256), 0, stream,
                           fp, fmap, tmap, ktab, out, mm);
    } else {
        dim3 g((NOUT + FTILE - 1) / FTILE, (NOUT + FTILE - 1) / FTILE);
        hipLaunchKernelGGL(gabor_main, g, dim3(256), 0, stream,
                           fp, fmap, tmap, out, mm);
    }

    int nblk = (IMG * IMG + 255) / 256;
    hipLaunchKernelGGL(border_copy, dim3(nblk), dim3(256), 0, stream, fp, out, mm);
    hipLaunchKernelGGL(finalize,    dim3(nblk), dim3(256), 0, stream, out, mm);
}